// Round 2
// baseline (70741.626 us; speedup 1.0000x reference)
//
#include <hip/hip_runtime.h>
#include <hip/hip_cooperative_groups.h>

namespace cg = cooperative_groups;

#define H 256
#define B 128
#define TE 240
#define TF 360
#define NK 241
#define BH (B*H)

__device__ __forceinline__ float sigm(float x){ return __builtin_amdgcn_rcpf(1.f+__expf(-x)); }
__device__ __forceinline__ float ftanh(float x){ float e=__expf(2.f*x); return 1.f-2.f*__builtin_amdgcn_rcpf(e+1.f); }
__device__ __forceinline__ float dot4(float4 a, float4 b){ return a.x*b.x+a.y*b.y+a.z*b.z+a.w*b.w; }

// ---------------- CNN ----------------
template<int IC, int OC, int IN_HW, int OUT_HW>
__global__ void conv_relu(const float* __restrict__ in, const float* __restrict__ w,
                          const float* __restrict__ bias, float* __restrict__ out)
{
    int idx = blockIdx.x * blockDim.x + threadIdx.x;
    constexpr int total = B * OC * OUT_HW * OUT_HW;
    if (idx >= total) return;
    int x  = idx % OUT_HW;
    int y  = (idx / OUT_HW) % OUT_HW;
    int oc = (idx / (OUT_HW * OUT_HW)) % OC;
    int b  = idx / (OUT_HW * OUT_HW * OC);
    float acc = bias[oc];
    const float* wp = w + (size_t)oc * IC * 9;
    const float* ip = in + (size_t)b * IC * IN_HW * IN_HW;
    for (int ic = 0; ic < IC; ++ic) {
        const float* ipc = ip + (size_t)ic * IN_HW * IN_HW;
        const float* wpc = wp + ic * 9;
        #pragma unroll
        for (int ky = 0; ky < 3; ++ky) {
            int iy = 2 * y - 1 + ky;
            if ((unsigned)iy >= (unsigned)IN_HW) continue;
            #pragma unroll
            for (int kx = 0; kx < 3; ++kx) {
                int ix = 2 * x - 1 + kx;
                if ((unsigned)ix >= (unsigned)IN_HW) continue;
                acc += ipc[iy * IN_HW + ix] * wpc[ky * 3 + kx];
            }
        }
    }
    out[idx] = fmaxf(acc, 0.f);
}

__global__ void pool_ef(const float* __restrict__ conv3, const float* __restrict__ ef_w,
                        const float* __restrict__ ef_b, float* __restrict__ keys)
{
    int b = blockIdx.x, tid = threadIdx.x;
    __shared__ float pooled[128];
    if (tid < 128) {
        const float* p = conv3 + (size_t)(b * 128 + tid) * 64;
        float s = 0.f;
        #pragma unroll 8
        for (int i = 0; i < 64; ++i) s += p[i];
        pooled[tid] = s * (1.f / 64.f);
    }
    __syncthreads();
    float acc = ef_b[tid];
    const float* wr = ef_w + (size_t)tid * 128;
    for (int c = 0; c < 128; ++c) acc += pooled[c] * wr[c];
    keys[((size_t)b * NK + 240) * H + tid] = acc;
}

// ---------------- persistent fused encoder+decoder ----------------
struct KParams {
    const float *hist;
    const float *e0_Wih,*e0_Whh,*e0_bih,*e0_bhh;
    const float *e1_Wih,*e1_Whh,*e1_bih,*e1_bhh;
    const float *aW_w,*aW_b,*av_w,*av_b;
    const float *d0_Wih,*d0_Whh,*d0_bih,*d0_bhh;
    const float *d1_Wih,*d1_Whh,*d1_bih,*d1_bhh;
    const float *o_w,*o_b;
    float *keys,*kp,*h0,*h1,*cfin1,*hd1,*hd2,*ctx,*part0,*part1,*curr,*preds;
};

__global__ __launch_bounds__(256) void fused_seq(KParams P)
{
    cg::grid_group grid = cg::this_grid();
    const int blk = blockIdx.x, tid = threadIdx.x;
    const int b = tid & 127, jj = tid >> 7;

    // LDS layout (floats):
    // sA [0,4096): enc weights (L0: Whh 2048 | L1: Wih 2048 + Whh 2048); later keysproj tile
    // sB [4096,8320): blk<128: d0_Wih ctx-part 2048 ; blk>=128: d0_Whh 2048 + d1_Whh 2048
    // sC [8320,9344): d1_Wih row j=blk (1024)
    // sD [9344,10624): attn scratch h2s/qs/als/red (4x256) + avs(256); gl aliases [0,512)
    // sE [10624,10688): biases + tiny weight cols
    __shared__ float smem[10688];
    float* sA = smem;
    float* sB = smem + 4096;
    float* sC = smem + 8320;
    float* sD = smem + 9344;
    float* sE = smem + 10624;

    const int j = (blk < 128 ? blk*2 : (blk-128)*2) + jj;

    // ---- stage static weights into LDS ----
    if (blk < 128) {
        const int j0 = blk*2;
        for (int i = tid; i < 2048; i += 256) {
            int q = i >> 9, r = i & 511, j2 = r >> 8, k = r & 255;
            sA[i] = P.e0_Whh[(size_t)((q<<8) + j0 + j2)*H + k];
            sB[i] = P.d0_Wih[(size_t)((q<<8) + j0 + j2)*258 + 2 + k];
        }
        if (tid < 8) {
            int q = tid >> 1, j2 = tid & 1, jw = j0 + j2;
            sE[tid]   = P.e0_bih[(q<<8)+jw] + P.e0_bhh[(q<<8)+jw];
            sE[8+tid] = P.d0_bih[(q<<8)+jw] + P.d0_bhh[(q<<8)+jw];
        }
        if (tid < 16) {
            int q = tid >> 2, r = tid & 3, j2 = r >> 1, c = r & 1;
            sE[20+tid] = P.d0_Wih[(size_t)((q<<8)+j0+j2)*258 + c];
            sE[36+tid] = P.e0_Wih[(size_t)((q<<8)+j0+j2)*2 + c];
        }
        sD[1024+tid] = P.av_w[tid];
    } else {
        const int j0 = (blk-128)*2;
        for (int i = tid; i < 2048; i += 256) {
            int q = i >> 9, r = i & 511, j2 = r >> 8, k = r & 255;
            int row = (q<<8) + j0 + j2;
            sA[i]      = P.e1_Wih[(size_t)row*H + k];
            sA[2048+i] = P.e1_Whh[(size_t)row*H + k];
            sB[i]      = P.d0_Whh[(size_t)row*H + k];
            sB[2048+i] = P.d1_Whh[(size_t)row*H + k];
        }
        if (tid < 8) {
            int q = tid >> 1, j2 = tid & 1, jw = j0 + j2;
            sE[tid] = P.e1_bih[(q<<8)+jw] + P.e1_bhh[(q<<8)+jw];
        }
    }
    for (int i = tid; i < 1024; i += 256) {
        int q = i >> 8, k = i & 255;
        sC[i] = P.d1_Wih[(size_t)((q<<8) + blk)*H + k];
    }
    if (tid < 4) sE[16+tid] = P.d1_bih[(tid<<8)+blk] + P.d1_bhh[(tid<<8)+blk];
    __syncthreads();

    float creg = 0.f;   // enc L0 c (blk<128, becomes decoder cd1) / enc L1 c (blk>=128)

    // ================= encoder: 241 pipelined phases =================
    for (int p = 0; p <= TE; ++p) {
        if (blk < 128) {
            if (p < TE) {
                float x0 = P.hist[(b*TE + p)*2], x1 = P.hist[(b*TE + p)*2 + 1];
                float g0 = sE[0+jj] + x0*sE[36+jj*2]    + x1*sE[36+jj*2+1];
                float g1 = sE[2+jj] + x0*sE[36+4+jj*2]  + x1*sE[36+4+jj*2+1];
                float g2 = sE[4+jj] + x0*sE[36+8+jj*2]  + x1*sE[36+8+jj*2+1];
                float g3 = sE[6+jj] + x0*sE[36+12+jj*2] + x1*sE[36+12+jj*2+1];
                if (p > 0) {
                    const float4* h4 = (const float4*)(P.h0 + (p&1)*BH + b*H);
                    const float4* w0 = (const float4*)(sA + jj*256);
                    const float4* w1 = (const float4*)(sA + 512 + jj*256);
                    const float4* w2 = (const float4*)(sA + 1024 + jj*256);
                    const float4* w3 = (const float4*)(sA + 1536 + jj*256);
                    #pragma unroll 4
                    for (int k = 0; k < 64; ++k) {
                        float4 hv = h4[k];
                        g0 += dot4(w0[k],hv); g1 += dot4(w1[k],hv);
                        g2 += dot4(w2[k],hv); g3 += dot4(w3[k],hv);
                    }
                }
                creg = sigm(g1)*creg + sigm(g0)*ftanh(g2);
                float hn = sigm(g3)*ftanh(creg);
                P.h0[((p+1)&1)*BH + b*H + j] = hn;
            }
        } else {
            if (p >= 1) {
                int s = p - 1;
                float g0 = sE[0+jj], g1 = sE[2+jj], g2 = sE[4+jj], g3 = sE[6+jj];
                const float4* x4  = (const float4*)(P.h0 + (p&1)*BH + b*H);
                const float4* wi0 = (const float4*)(sA + jj*256);
                const float4* wi1 = (const float4*)(sA + 512 + jj*256);
                const float4* wi2 = (const float4*)(sA + 1024 + jj*256);
                const float4* wi3 = (const float4*)(sA + 1536 + jj*256);
                if (s > 0) {
                    const float4* h4  = (const float4*)(P.h1 + ((p-1)&1)*BH + b*H);
                    const float4* wh0 = (const float4*)(sA + 2048 + jj*256);
                    const float4* wh1 = (const float4*)(sA + 2048 + 512 + jj*256);
                    const float4* wh2 = (const float4*)(sA + 2048 + 1024 + jj*256);
                    const float4* wh3 = (const float4*)(sA + 2048 + 1536 + jj*256);
                    #pragma unroll 2
                    for (int k = 0; k < 64; ++k) {
                        float4 xv = x4[k], hv = h4[k];
                        g0 += dot4(wi0[k],xv) + dot4(wh0[k],hv);
                        g1 += dot4(wi1[k],xv) + dot4(wh1[k],hv);
                        g2 += dot4(wi2[k],xv) + dot4(wh2[k],hv);
                        g3 += dot4(wi3[k],xv) + dot4(wh3[k],hv);
                    }
                } else {
                    #pragma unroll 4
                    for (int k = 0; k < 64; ++k) {
                        float4 xv = x4[k];
                        g0 += dot4(wi0[k],xv); g1 += dot4(wi1[k],xv);
                        g2 += dot4(wi2[k],xv); g3 += dot4(wi3[k],xv);
                    }
                }
                creg = sigm(g1)*creg + sigm(g0)*ftanh(g2);
                float hn = sigm(g3)*ftanh(creg);
                P.h1[(p&1)*BH + b*H + j] = hn;
                P.keys[((size_t)b*NK + s)*H + j] = hn;
                if (p == TE) P.cfin1[b*H + j] = creg;
            }
        }
        grid.sync();
    }

    // ================= keys_proj GEMM + decoder state init =================
    {
        for (int i = blk*256 + tid; i < BH; i += 65536) {
            P.hd1[i] = P.h0[i];   // final layer0 h lives in buffer 0
            P.hd2[i] = P.h1[i];   // final layer1 h lives in buffer 0
        }
        if (blk == 0) {
            int bb = tid >> 1, c = tid & 1;
            P.curr[tid] = P.hist[(bb*TE + TE-1)*2 + c];
        }
        const float4* wk4 = (const float4*)(P.aW_w + (size_t)tid*(2*H) + H);
        float bias_g = P.aW_b[tid];
        for (int ch = blk; ch < 1928; ch += 256) {
            int row0 = ch * 16;
            __syncthreads();
            for (int i = tid; i < 4096; i += 256) sA[i] = P.keys[(size_t)row0*H + i];
            __syncthreads();
            float acc[16];
            #pragma unroll
            for (int r = 0; r < 16; ++r) acc[r] = bias_g;
            for (int k = 0; k < 64; ++k) {
                float4 w = wk4[k];
                #pragma unroll
                for (int r = 0; r < 16; ++r)
                    acc[r] += dot4(((const float4*)(sA + r*256))[k], w);
            }
            #pragma unroll
            for (int r = 0; r < 16; ++r) P.kp[(size_t)(row0+r)*H + tid] = acc[r];
        }
    }
    grid.sync();

    float cdC = P.cfin1[b*H + blk];   // decoder cd2 (used by jj==0 threads)

    // ================= decoder: 360 steps x 3 stages =================
    for (int t = 0; t < TF; ++t) {
        // ---- stage A: attention (blk<128) || d0_Whh@hd1 partial (blk>=128) ----
        if (blk < 128) {
            const int bb = blk;
            sD[tid] = P.hd2[(t&1)*BH + bb*H + tid];
            __syncthreads();
            if (t > 0 && tid < 2) {
                float acc = P.o_b[tid];
                const float* wr = P.o_w + tid*H;
                for (int k = 0; k < H; ++k) acc += sD[k]*wr[k];
                float c = P.curr[bb*2+tid] + acc;
                P.curr[bb*2+tid] = c;
                P.preds[((size_t)bb*TF + (t-1))*2 + tid] = c;
            }
            {
                float accq = 0.f;
                const float4* wq = (const float4*)(P.aW_w + (size_t)tid*(2*H));
                const float4* h24 = (const float4*)sD;
                #pragma unroll 4
                for (int k = 0; k < 64; ++k) accq += dot4(wq[k], h24[k]);
                sD[256+tid] = accq;
            }
            __syncthreads();
            float ex = 0.f;
            if (tid < NK) {
                float acc = P.av_b[0];
                const float4* kpr = (const float4*)(P.kp + ((size_t)bb*NK + tid)*H);
                const float4* q4 = (const float4*)(sD+256);
                const float4* a4 = (const float4*)(sD+1024);
                #pragma unroll 2
                for (int k = 0; k < 64; ++k) {
                    float4 kk = kpr[k], qq = q4[k], aa = a4[k];
                    acc += aa.x*ftanh(qq.x+kk.x) + aa.y*ftanh(qq.y+kk.y)
                         + aa.z*ftanh(qq.z+kk.z) + aa.w*ftanh(qq.w+kk.w);
                }
                ex = __expf(acc);   // |energy| <= ~13 -> exp safe without max-sub
            }
            sD[768+tid] = ex;
            __syncthreads();
            for (int s2 = 128; s2 > 0; s2 >>= 1) {
                if (tid < s2) sD[768+tid] += sD[768+tid+s2];
                __syncthreads();
            }
            float inv = 1.f / sD[768];
            if (tid < NK) sD[512+tid] = ex * inv;
            __syncthreads();
            {
                float acc = 0.f;
                const float* kb = P.keys + (size_t)bb*NK*H + tid;
                #pragma unroll 4
                for (int k2 = 0; k2 < NK; ++k2) acc += sD[512+k2]*kb[(size_t)k2*H];
                P.ctx[bb*H + tid] = acc;
            }
        } else {
            const float4* h4 = (const float4*)(P.hd1 + (t&1)*BH + b*H);
            const float4* w0 = (const float4*)(sB + jj*256);
            const float4* w1 = (const float4*)(sB + 512 + jj*256);
            const float4* w2 = (const float4*)(sB + 1024 + jj*256);
            const float4* w3 = (const float4*)(sB + 1536 + jj*256);
            float g0=0.f, g1=0.f, g2=0.f, g3=0.f;
            #pragma unroll 4
            for (int k = 0; k < 64; ++k) {
                float4 hv = h4[k];
                g0 += dot4(w0[k],hv); g1 += dot4(w1[k],hv);
                g2 += dot4(w2[k],hv); g3 += dot4(w3[k],hv);
            }
            P.part0[(size_t)(0*H + j)*B + b] = g0;
            P.part0[(size_t)(1*H + j)*B + b] = g1;
            P.part0[(size_t)(2*H + j)*B + b] = g2;
            P.part0[(size_t)(3*H + j)*B + b] = g3;
        }
        grid.sync();

        // ---- stage B: cell0 finish (blk<128) || d1_Whh@hd2 partial (blk>=128) ----
        if (blk < 128) {
            float u0 = P.curr[b*2], u1 = P.curr[b*2+1];
            float g[4];
            #pragma unroll
            for (int q = 0; q < 4; ++q)
                g[q] = sE[8+q*2+jj] + P.part0[(size_t)(q*H + j)*B + b]
                     + u0*sE[20+q*4+jj*2] + u1*sE[20+q*4+jj*2+1];
            const float4* c4 = (const float4*)(P.ctx + b*H);
            const float4* w0 = (const float4*)(sB + jj*256);
            const float4* w1 = (const float4*)(sB + 512 + jj*256);
            const float4* w2 = (const float4*)(sB + 1024 + jj*256);
            const float4* w3 = (const float4*)(sB + 1536 + jj*256);
            #pragma unroll 4
            for (int k = 0; k < 64; ++k) {
                float4 cv = c4[k];
                g[0] += dot4(w0[k],cv); g[1] += dot4(w1[k],cv);
                g[2] += dot4(w2[k],cv); g[3] += dot4(w3[k],cv);
            }
            creg = sigm(g[1])*creg + sigm(g[0])*ftanh(g[2]);
            float hn = sigm(g[3])*ftanh(creg);
            P.hd1[((t+1)&1)*BH + b*H + j] = hn;
        } else {
            const float4* h4 = (const float4*)(P.hd2 + (t&1)*BH + b*H);
            const float4* w0 = (const float4*)(sB + 2048 + jj*256);
            const float4* w1 = (const float4*)(sB + 2048 + 512 + jj*256);
            const float4* w2 = (const float4*)(sB + 2048 + 1024 + jj*256);
            const float4* w3 = (const float4*)(sB + 2048 + 1536 + jj*256);
            float g0=0.f, g1=0.f, g2=0.f, g3=0.f;
            #pragma unroll 4
            for (int k = 0; k < 64; ++k) {
                float4 hv = h4[k];
                g0 += dot4(w0[k],hv); g1 += dot4(w1[k],hv);
                g2 += dot4(w2[k],hv); g3 += dot4(w3[k],hv);
            }
            P.part1[(size_t)(0*H + j)*B + b] = g0;
            P.part1[(size_t)(1*H + j)*B + b] = g1;
            P.part1[(size_t)(2*H + j)*B + b] = g2;
            P.part1[(size_t)(3*H + j)*B + b] = g3;
        }
        grid.sync();

        // ---- stage C: cell1 finish (all blocks, j = blk, 2 gates/thread) ----
        {
            const float4* h4  = (const float4*)(P.hd1 + ((t+1)&1)*BH + b*H);
            const float4* wA4 = (const float4*)(sC + (jj*2)*256);
            const float4* wB4 = (const float4*)(sC + (jj*2+1)*256);
            float ga = sE[16+jj*2]   + P.part1[(size_t)((jj*2)*H + blk)*B + b];
            float gb = sE[16+jj*2+1] + P.part1[(size_t)((jj*2+1)*H + blk)*B + b];
            #pragma unroll 4
            for (int k = 0; k < 64; ++k) {
                float4 hv = h4[k];
                ga += dot4(wA4[k],hv); gb += dot4(wB4[k],hv);
            }
            sD[(jj*2)*128 + b] = ga;
            sD[(jj*2+1)*128 + b] = gb;
            __syncthreads();
            if (jj == 0) {
                float gi = sD[b], gf = sD[128+b], gg = sD[256+b], go = sD[384+b];
                cdC = sigm(gf)*cdC + sigm(gi)*ftanh(gg);
                float hn = sigm(go)*ftanh(cdC);
                P.hd2[((t+1)&1)*BH + b*H + blk] = hn;
            }
        }
        grid.sync();
    }

    // ---- epilogue: pred[359] ----
    if (blk < 128) {
        sD[tid] = P.hd2[0*BH + blk*H + tid];   // TF even -> final hd2 in buffer 0
        __syncthreads();
        if (tid < 2) {
            float acc = P.o_b[tid];
            const float* wr = P.o_w + tid*H;
            for (int k = 0; k < H; ++k) acc += sD[k]*wr[k];
            P.preds[((size_t)blk*TF + TF-1)*2 + tid] = P.curr[blk*2+tid] + acc;
        }
    }
}

extern "C" void kernel_launch(void* const* d_in, const int* in_sizes, int n_in,
                              void* d_out, int out_size, void* d_ws, size_t ws_size,
                              hipStream_t stream)
{
    const float* hist   = (const float*)d_in[0];
    const float* env    = (const float*)d_in[1];
    const float* e0_Wih = (const float*)d_in[2];
    const float* e0_Whh = (const float*)d_in[3];
    const float* e0_bih = (const float*)d_in[4];
    const float* e0_bhh = (const float*)d_in[5];
    const float* e1_Wih = (const float*)d_in[6];
    const float* e1_Whh = (const float*)d_in[7];
    const float* e1_bih = (const float*)d_in[8];
    const float* e1_bhh = (const float*)d_in[9];
    const float* c1w = (const float*)d_in[10];
    const float* c1b = (const float*)d_in[11];
    const float* c2w = (const float*)d_in[12];
    const float* c2b = (const float*)d_in[13];
    const float* c3w = (const float*)d_in[14];
    const float* c3b = (const float*)d_in[15];
    const float* ef_w = (const float*)d_in[16];
    const float* ef_b = (const float*)d_in[17];
    const float* aW_w = (const float*)d_in[18];
    const float* aW_b = (const float*)d_in[19];
    const float* av_w = (const float*)d_in[20];
    const float* av_b = (const float*)d_in[21];
    const float* d0_Wih = (const float*)d_in[22];
    const float* d0_Whh = (const float*)d_in[23];
    const float* d0_bih = (const float*)d_in[24];
    const float* d0_bhh = (const float*)d_in[25];
    const float* d1_Wih = (const float*)d_in[26];
    const float* d1_Whh = (const float*)d_in[27];
    const float* d1_bih = (const float*)d_in[28];
    const float* d1_bhh = (const float*)d_in[29];
    const float* o_w = (const float*)d_in[30];
    const float* o_b = (const float*)d_in[31];

    float* ws = (float*)d_ws;
    size_t off = 0;
    float* keys = ws;               off += (size_t)B*NK*H;
    float* kp   = ws + off;         off += (size_t)B*NK*H;
    // conv scratch aliases kp (consumed before kp is written)
    float* convA = kp;
    float* convB = kp + 4194304;
    float* convC = kp + 6291456;
    float* h0    = ws + off; off += 2*BH;
    float* h1    = ws + off; off += 2*BH;
    float* cfin1 = ws + off; off += BH;
    float* hd1   = ws + off; off += 2*BH;
    float* hd2   = ws + off; off += 2*BH;
    float* ctx   = ws + off; off += BH;
    float* part0 = ws + off; off += (size_t)4*H*B;
    float* part1 = ws + off; off += (size_t)4*H*B;
    float* curr  = ws + off; off += B*2;

    // ---- CNN branch (one-shot) ----
    conv_relu<18, 32, 64, 32><<<(B*32*32*32)/256, 256, 0, stream>>>(env, c1w, c1b, convA);
    conv_relu<32, 64, 32, 16><<<(B*64*16*16)/256, 256, 0, stream>>>(convA, c2w, c2b, convB);
    conv_relu<64, 128, 16, 8><<<(B*128*8*8)/256, 256, 0, stream>>>(convB, c3w, c3b, convC);
    pool_ef<<<B, 256, 0, stream>>>(convC, ef_w, ef_b, keys);

    // ---- persistent cooperative kernel: encoder + keys_proj + decoder ----
    KParams Pk = {
        hist,
        e0_Wih, e0_Whh, e0_bih, e0_bhh,
        e1_Wih, e1_Whh, e1_bih, e1_bhh,
        aW_w, aW_b, av_w, av_b,
        d0_Wih, d0_Whh, d0_bih, d0_bhh,
        d1_Wih, d1_Whh, d1_bih, d1_bhh,
        o_w, o_b,
        keys, kp, h0, h1, cfin1, hd1, hd2, ctx, part0, part1, curr, (float*)d_out
    };
    void* args[] = { &Pk };
    hipLaunchCooperativeKernel((void*)fused_seq, dim3(256), dim3(256), args, 0, stream);
}

// Round 3
// 26626.434 us; speedup vs baseline: 2.6568x; 2.6568x over previous
//
#include <hip/hip_runtime.h>

#define H 256
#define B 128
#define TE 240
#define TF 360
#define NK 241
#define BH (B*H)

__device__ __forceinline__ float sigm(float x){ return __builtin_amdgcn_rcpf(1.f+__expf(-x)); }
__device__ __forceinline__ float ftanh(float x){ float e=__expf(2.f*x); return 1.f-2.f*__builtin_amdgcn_rcpf(e+1.f); }
__device__ __forceinline__ float dot4(float4 a, float4 b){ return a.x*b.x+a.y*b.y+a.z*b.z+a.w*b.w; }

// ---- coherent (L2-bypassing) access helpers ----
__device__ __forceinline__ float gld(const float* p){
    return __hip_atomic_load((const float*)p, __ATOMIC_RELAXED, __HIP_MEMORY_SCOPE_AGENT);
}
__device__ __forceinline__ void gst(float* p, float v){
    __hip_atomic_store(p, v, __ATOMIC_RELAXED, __HIP_MEMORY_SCOPE_AGENT);
}
// batched 16x dwordx4 coherent loads: issue all, then one wait
__device__ __forceinline__ void issue16(float4* st, const float4* p){
    #pragma unroll
    for (int i = 0; i < 16; ++i)
        asm volatile("global_load_dwordx4 %0, %1, off offset:%2 sc0 sc1"
                     : "=v"(st[i]) : "v"(p), "n"(i*16));
}
__device__ __forceinline__ void vmwait(){
    asm volatile("s_waitcnt vmcnt(0)" ::: "memory");
    __builtin_amdgcn_sched_barrier(0);
}

// ---- custom grid barrier: monotonic counters, relaxed agent atomics (no L2 flush) ----
__device__ __forceinline__ void gbar(unsigned* bar, unsigned step){
    asm volatile("s_waitcnt vmcnt(0)" ::: "memory");
    __syncthreads();                // every wave drained its own vmem before this
    if (threadIdx.x == 0){
        unsigned g = (unsigned)blockIdx.x & 7u;
        unsigned o = __hip_atomic_fetch_add(&bar[g*32], 1u, __ATOMIC_RELAXED, __HIP_MEMORY_SCOPE_AGENT);
        if ((o & 31u) == 31u){
            unsigned r = __hip_atomic_fetch_add(&bar[256+32], 1u, __ATOMIC_RELAXED, __HIP_MEMORY_SCOPE_AGENT);
            if ((r & 7u) == 7u)
                __hip_atomic_fetch_add(&bar[256+64], 1u, __ATOMIC_RELAXED, __HIP_MEMORY_SCOPE_AGENT);
        }
        while (__hip_atomic_load(&bar[256+64], __ATOMIC_RELAXED, __HIP_MEMORY_SCOPE_AGENT) < step)
            __builtin_amdgcn_s_sleep(2);
    }
    __syncthreads();
}

// ---------------- CNN (one-shot, unchanged) ----------------
template<int IC, int OC, int IN_HW, int OUT_HW>
__global__ void conv_relu(const float* __restrict__ in, const float* __restrict__ w,
                          const float* __restrict__ bias, float* __restrict__ out)
{
    int idx = blockIdx.x * blockDim.x + threadIdx.x;
    constexpr int total = B * OC * OUT_HW * OUT_HW;
    if (idx >= total) return;
    int x  = idx % OUT_HW;
    int y  = (idx / OUT_HW) % OUT_HW;
    int oc = (idx / (OUT_HW * OUT_HW)) % OC;
    int b  = idx / (OUT_HW * OUT_HW * OC);
    float acc = bias[oc];
    const float* wp = w + (size_t)oc * IC * 9;
    const float* ip = in + (size_t)b * IC * IN_HW * IN_HW;
    for (int ic = 0; ic < IC; ++ic) {
        const float* ipc = ip + (size_t)ic * IN_HW * IN_HW;
        const float* wpc = wp + ic * 9;
        #pragma unroll
        for (int ky = 0; ky < 3; ++ky) {
            int iy = 2 * y - 1 + ky;
            if ((unsigned)iy >= (unsigned)IN_HW) continue;
            #pragma unroll
            for (int kx = 0; kx < 3; ++kx) {
                int ix = 2 * x - 1 + kx;
                if ((unsigned)ix >= (unsigned)IN_HW) continue;
                acc += ipc[iy * IN_HW + ix] * wpc[ky * 3 + kx];
            }
        }
    }
    out[idx] = fmaxf(acc, 0.f);
}

__global__ void pool_ef(const float* __restrict__ conv3, const float* __restrict__ ef_w,
                        const float* __restrict__ ef_b, float* __restrict__ keys)
{
    int b = blockIdx.x, tid = threadIdx.x;
    __shared__ float pooled[128];
    if (tid < 128) {
        const float* p = conv3 + (size_t)(b * 128 + tid) * 64;
        float s = 0.f;
        #pragma unroll 8
        for (int i = 0; i < 64; ++i) s += p[i];
        pooled[tid] = s * (1.f / 64.f);
    }
    __syncthreads();
    if (tid < 256) {
        float acc = ef_b[tid];
        const float* wr = ef_w + (size_t)tid * 128;
        for (int c = 0; c < 128; ++c) acc += pooled[c] * wr[c];
        keys[((size_t)b * NK + 240) * H + tid] = acc;
    }
}

// ---------------- persistent fused encoder+keysproj+decoder ----------------
struct KP2 {
    const float *hist;
    const float *e0_Wih,*e0_Whh,*e0_bih,*e0_bhh;
    const float *e1_Wih,*e1_Whh,*e1_bih,*e1_bhh;
    const float *aW_w,*aW_b,*av_w,*av_b;
    const float *d0_Wih,*d0_Whh,*d0_bih,*d0_bhh;
    const float *d1_Wih,*d1_Whh,*d1_bih,*d1_bhh;
    const float *o_w,*o_b;
    float *keys,*kp,*h0,*h1,*cfin1,*ctx,*part0,*part1,*curr,*preds;
    unsigned *bar;
};

__global__ __launch_bounds__(512) void fused2(KP2 P)
{
    const int blk = blockIdx.x, tid = threadIdx.x;
    const int b = tid & 127, kk = tid >> 7;        // compute mapping: batch row, K-quarter
    const int fb = tid & 127, fj = tid >> 7;       // finalize mapping (tid<256): (batch, j-of-pair)

    // LDS: sA[4096] enc weights (+d0_Wih-ctx for blk<128), sB[4096] dec Whh (blk>=128),
    // sC[1024] d1_Wih row j=blk, sPart[4096] partial dots / keysproj tile, sD[1792] attn, sE[64] biases
    __shared__ float sA[4096], sB[4096], sC[1024], sPart[4096], sD[1792], sE[64];

    // ---- stage static weights into LDS ----
    if (blk < 128) {
        const int j0 = blk*2;
        for (int i = tid; i < 2048; i += 512) {
            int m = i >> 8, k = i & 255, jjx = m >> 2, q = m & 3;
            int row = q*256 + j0 + jjx;
            sA[i]        = P.e0_Whh[(size_t)row*256 + k];
            sA[2048 + i] = P.d0_Wih[(size_t)row*258 + 2 + k];
        }
        if (tid < 8) {
            int q = tid & 3, jjx = tid >> 2;
            int row = q*256 + j0 + jjx;
            sE[tid]     = P.e0_bih[row] + P.e0_bhh[row];
            sE[8 + tid] = P.d0_bih[row] + P.d0_bhh[row];
        }
        if (tid < 16) {
            int m = tid >> 1, c = tid & 1;
            int q = m & 3, jjx = m >> 2;
            int row = q*256 + j0 + jjx;
            sE[32 + tid] = P.e0_Wih[(size_t)row*2 + c];
            sE[48 + tid] = P.d0_Wih[(size_t)row*258 + c];
        }
        if (tid < 256) sD[1536 + tid] = P.av_w[tid];
    } else {
        const int j0 = (blk-128)*2;
        for (int i = tid; i < 2048; i += 512) {
            int m = i >> 8, k = i & 255, jjx = m >> 2, q = m & 3;
            int row = q*256 + j0 + jjx;
            sA[i]        = P.e1_Wih[(size_t)row*256 + k];
            sA[2048 + i] = P.e1_Whh[(size_t)row*256 + k];
            sB[i]        = P.d0_Whh[(size_t)row*256 + k];
            sB[2048 + i] = P.d1_Whh[(size_t)row*256 + k];
        }
        if (tid < 8) {
            int q = tid & 3, jjx = tid >> 2;
            int row = q*256 + j0 + jjx;
            sE[tid] = P.e1_bih[row] + P.e1_bhh[row];
        }
    }
    for (int i = tid; i < 1024; i += 512) {
        int q = i >> 8, k = i & 255;
        sC[i] = P.d1_Wih[(size_t)(q*256 + blk)*256 + k];
    }
    if (tid < 4) sE[16 + tid] = P.d1_bih[tid*256 + blk] + P.d1_bhh[tid*256 + blk];
    __syncthreads();

    unsigned bstep = 0;
    float creg = 0.f;     // enc L0 c (-> decoder cd1) on blk<128 / enc L1 c on blk>=128 (tid<256)

    // ================= encoder: 241 pipelined phases =================
    for (int p = 0; p <= TE; ++p) {
        if (blk < 128) {
            if (p < TE) {
                float acc[8] = {0,0,0,0,0,0,0,0};
                if (p > 0) {
                    float4 st[16];
                    issue16(st, (const float4*)(P.h0 + (size_t)(p&1)*BH + b*H + kk*64));
                    vmwait();
                    #pragma unroll
                    for (int m = 0; m < 8; ++m) {
                        const float4* w = (const float4*)(sA + m*256 + kk*64);
                        float a = 0.f;
                        #pragma unroll
                        for (int i = 0; i < 16; ++i) a += dot4(st[i], w[i]);
                        acc[m] = a;
                    }
                }
                #pragma unroll
                for (int m = 0; m < 8; ++m) sPart[(kk*8+m)*128 + b] = acc[m];
            }
        } else {
            if (p >= 1) {
                float acc[8] = {0,0,0,0,0,0,0,0};
                float4 stx[16], sth[16];
                issue16(stx, (const float4*)(P.h0 + (size_t)(p&1)*BH + b*H + kk*64));
                if (p > 1) issue16(sth, (const float4*)(P.h1 + (size_t)((p-1)&1)*BH + b*H + kk*64));
                vmwait();
                #pragma unroll
                for (int m = 0; m < 8; ++m) {
                    const float4* wi = (const float4*)(sA + m*256 + kk*64);
                    float a = 0.f;
                    #pragma unroll
                    for (int i = 0; i < 16; ++i) a += dot4(stx[i], wi[i]);
                    acc[m] = a;
                }
                if (p > 1) {
                    #pragma unroll
                    for (int m = 0; m < 8; ++m) {
                        const float4* wh = (const float4*)(sA + 2048 + m*256 + kk*64);
                        float a = acc[m];
                        #pragma unroll
                        for (int i = 0; i < 16; ++i) a += dot4(sth[i], wh[i]);
                        acc[m] = a;
                    }
                }
                #pragma unroll
                for (int m = 0; m < 8; ++m) sPart[(kk*8+m)*128 + b] = acc[m];
            }
        }
        __syncthreads();
        if (tid < 256) {
            if (blk < 128 && p < TE) {
                float x0 = P.hist[((size_t)fb*TE + p)*2], x1 = P.hist[((size_t)fb*TE + p)*2 + 1];
                float g[4];
                #pragma unroll
                for (int q = 0; q < 4; ++q) {
                    int m = fj*4 + q;
                    float gg = sE[m] + x0*sE[32+2*m] + x1*sE[33+2*m];
                    if (p > 0) {
                        #pragma unroll
                        for (int kx = 0; kx < 4; ++kx) gg += sPart[(kx*8+m)*128 + fb];
                    }
                    g[q] = gg;
                }
                creg = sigm(g[1])*creg + sigm(g[0])*ftanh(g[2]);
                float hn = sigm(g[3])*ftanh(creg);
                gst(P.h0 + (size_t)((p+1)&1)*BH + fb*H + (blk*2+fj), hn);
            } else if (blk >= 128 && p >= 1) {
                int jg = (blk-128)*2 + fj, s = p-1;
                float g[4];
                #pragma unroll
                for (int q = 0; q < 4; ++q) {
                    int m = fj*4 + q;
                    float gg = sE[m];
                    #pragma unroll
                    for (int kx = 0; kx < 4; ++kx) gg += sPart[(kx*8+m)*128 + fb];
                    g[q] = gg;
                }
                creg = sigm(g[1])*creg + sigm(g[0])*ftanh(g[2]);
                float hn = sigm(g[3])*ftanh(creg);
                gst(P.h1 + (size_t)(p&1)*BH + fb*H + jg, hn);
                gst(P.keys + ((size_t)fb*NK + s)*H + jg, hn);
                if (s == TE-1) gst(P.cfin1 + (size_t)fb*H + jg, creg);
            }
        }
        gbar(P.bar, ++bstep);
    }

    // ================= keys_proj: kp = keys @ Wk^T + aW_b =================
    {
        const float4* wk4 = (const float4*)(P.aW_w + (size_t)(tid & 255)*512 + 256);
        float biasg = P.aW_b[tid & 255];
        for (int ch = blk; ch < (B*NK)/16; ch += 256) {
            int row0 = ch * 16;
            __syncthreads();
            for (int i = tid; i < 4096; i += 512) sPart[i] = P.keys[(size_t)row0*256 + i];
            __syncthreads();
            if (tid < 256) {
                float acc[16];
                #pragma unroll
                for (int r = 0; r < 16; ++r) acc[r] = biasg;
                for (int k = 0; k < 64; ++k) {
                    float4 w = wk4[k];
                    #pragma unroll
                    for (int r = 0; r < 16; ++r)
                        acc[r] += dot4(((const float4*)(sPart + r*256))[k], w);
                }
                #pragma unroll
                for (int r = 0; r < 16; ++r) gst(P.kp + (size_t)(row0+r)*256 + tid, acc[r]);
            }
        }
    }
    gbar(P.bar, ++bstep);

    float cdC = 0.f;
    if (tid < 128) cdC = gld(P.cfin1 + (size_t)tid*256 + blk);

    // ================= decoder: 360 steps x 3 stages =================
    for (int t = 0; t < TF; ++t) {
        // ---- stage A: attention (blk<128) || d0_Whh @ hd1 partial (blk>=128) ----
        if (blk < 128) {
            const int bb = blk;
            if (tid < 256) sD[tid] = gld(P.h1 + (size_t)(t&1)*BH + bb*H + tid);
            __syncthreads();
            if (t == 0) {
                if (tid < 2) gst(P.curr + bb*2 + tid, P.hist[((size_t)bb*TE + TE-1)*2 + tid]);
            } else if (tid < 64) {
                int c = tid >> 5, l = tid & 31;
                float a = 0.f;
                for (int k = l; k < 256; k += 32) a += sD[k]*P.o_w[c*256+k];
                #pragma unroll
                for (int mk = 16; mk >= 1; mk >>= 1) a += __shfl_xor(a, mk, 32);
                if (l == 0) {
                    float cv = gld(P.curr + bb*2 + c) + P.o_b[c] + a;
                    gst(P.curr + bb*2 + c, cv);
                    P.preds[((size_t)bb*TF + (t-1))*2 + c] = cv;
                }
            }
            // q = Wq @ h2  (2 threads per output)
            {
                int h = tid >> 1, hf = tid & 1;
                const float4* w4 = (const float4*)(P.aW_w + (size_t)h*512 + hf*128);
                const float4* h4 = (const float4*)(sD + hf*128);
                float a = 0.f;
                #pragma unroll 8
                for (int i = 0; i < 32; ++i) a += dot4(w4[i], h4[i]);
                sD[512 + tid] = a;
            }
            __syncthreads();
            if (tid < 256) sD[256 + tid] = sD[512 + 2*tid] + sD[512 + 2*tid + 1];
            __syncthreads();
            // energy partials (2 threads per key)
            {
                int k = tid >> 1, hf = tid & 1;
                float a = 0.f;
                if (k < NK) {
                    const float4* kp4 = (const float4*)(P.kp + ((size_t)bb*NK + k)*256 + hf*128);
                    const float4* q4  = (const float4*)(sD + 256 + hf*128);
                    const float4* a4  = (const float4*)(sD + 1536 + hf*128);
                    #pragma unroll 4
                    for (int i = 0; i < 32; ++i) {
                        float4 kv = kp4[i], qv = q4[i], av = a4[i];
                        a += av.x*ftanh(qv.x+kv.x) + av.y*ftanh(qv.y+kv.y)
                           + av.z*ftanh(qv.z+kv.z) + av.w*ftanh(qv.w+kv.w);
                    }
                }
                sD[512 + tid] = a;
            }
            __syncthreads();
            float ex = 0.f;
            if (tid < NK) ex = __expf(sD[512 + 2*tid] + sD[512 + 2*tid + 1] + P.av_b[0]);
            if (tid < 256) sD[1024 + tid] = ex;
            __syncthreads();
            if (tid < 128) sD[512 + tid] = sD[1024 + tid] + sD[1024 + tid + 128];
            __syncthreads();
            #pragma unroll
            for (int s2 = 64; s2 >= 1; s2 >>= 1) {
                if (tid < s2) sD[512 + tid] += sD[512 + tid + s2];
                __syncthreads();
            }
            float inv = __builtin_amdgcn_rcpf(sD[512]);
            if (tid < 256) sD[1024 + tid] = ex * inv;
            __syncthreads();
            // ctx = alpha @ keys  (2 key-partitions x 256 cols)
            {
                int h = tid & 255, pp = tid >> 8;
                int k0 = pp*121, kn = 121 - pp;
                float a = 0.f;
                const float* kb = P.keys + ((size_t)bb*NK + k0)*256 + h;
                for (int k2 = 0; k2 < kn; ++k2) a += sD[1024 + k0 + k2]*kb[(size_t)k2*256];
                sD[512 + tid] = a;
            }
            __syncthreads();
            if (tid < 256) gst(P.ctx + (size_t)bb*H + tid, sD[512+tid] + sD[768+tid]);
        } else {
            float4 st[16];
            issue16(st, (const float4*)(P.h0 + (size_t)(t&1)*BH + b*H + kk*64));
            vmwait();
            float acc[8];
            #pragma unroll
            for (int m = 0; m < 8; ++m) {
                const float4* w = (const float4*)(sB + m*256 + kk*64);
                float a = 0.f;
                #pragma unroll
                for (int i = 0; i < 16; ++i) a += dot4(st[i], w[i]);
                acc[m] = a;
            }
            #pragma unroll
            for (int m = 0; m < 8; ++m) sPart[(kk*8+m)*128 + b] = acc[m];
            __syncthreads();
            if (tid < 256) {
                int jg = (blk-128)*2 + fj;
                #pragma unroll
                for (int q = 0; q < 4; ++q) {
                    int m = fj*4 + q;
                    float gg = sPart[(0*8+m)*128+fb] + sPart[(1*8+m)*128+fb]
                             + sPart[(2*8+m)*128+fb] + sPart[(3*8+m)*128+fb];
                    gst(P.part0 + ((size_t)(q*256 + jg))*128 + fb, gg);
                }
            }
        }
        gbar(P.bar, ++bstep);

        // ---- stage B: cell0 finish (blk<128) || d1_Whh @ hd2 partial (blk>=128) ----
        if (blk < 128) {
            float4 st[16];
            issue16(st, (const float4*)(P.ctx + (size_t)b*H + kk*64));
            vmwait();
            float acc[8];
            #pragma unroll
            for (int m = 0; m < 8; ++m) {
                const float4* w = (const float4*)(sA + 2048 + m*256 + kk*64);
                float a = 0.f;
                #pragma unroll
                for (int i = 0; i < 16; ++i) a += dot4(st[i], w[i]);
                acc[m] = a;
            }
            #pragma unroll
            for (int m = 0; m < 8; ++m) sPart[(kk*8+m)*128 + b] = acc[m];
            __syncthreads();
            if (tid < 256) {
                int jg = blk*2 + fj;
                float u0 = gld(P.curr + fb*2), u1 = gld(P.curr + fb*2 + 1);
                float g[4];
                #pragma unroll
                for (int q = 0; q < 4; ++q) {
                    int m = fj*4 + q;
                    float gg = sE[8+m] + u0*sE[48+2*m] + u1*sE[49+2*m]
                             + gld(P.part0 + ((size_t)(q*256 + jg))*128 + fb);
                    #pragma unroll
                    for (int kx = 0; kx < 4; ++kx) gg += sPart[(kx*8+m)*128 + fb];
                    g[q] = gg;
                }
                creg = sigm(g[1])*creg + sigm(g[0])*ftanh(g[2]);
                float hn = sigm(g[3])*ftanh(creg);
                gst(P.h0 + (size_t)((t+1)&1)*BH + fb*H + jg, hn);
            }
        } else {
            float4 st[16];
            issue16(st, (const float4*)(P.h1 + (size_t)(t&1)*BH + b*H + kk*64));
            vmwait();
            float acc[8];
            #pragma unroll
            for (int m = 0; m < 8; ++m) {
                const float4* w = (const float4*)(sB + 2048 + m*256 + kk*64);
                float a = 0.f;
                #pragma unroll
                for (int i = 0; i < 16; ++i) a += dot4(st[i], w[i]);
                acc[m] = a;
            }
            #pragma unroll
            for (int m = 0; m < 8; ++m) sPart[(kk*8+m)*128 + b] = acc[m];
            __syncthreads();
            if (tid < 256) {
                int jg = (blk-128)*2 + fj;
                #pragma unroll
                for (int q = 0; q < 4; ++q) {
                    int m = fj*4 + q;
                    float gg = sPart[(0*8+m)*128+fb] + sPart[(1*8+m)*128+fb]
                             + sPart[(2*8+m)*128+fb] + sPart[(3*8+m)*128+fb];
                    gst(P.part1 + ((size_t)(q*256 + jg))*128 + fb, gg);
                }
            }
        }
        gbar(P.bar, ++bstep);

        // ---- stage C: cell1 finish (all blocks, j = blk) ----
        {
            float4 st[16];
            issue16(st, (const float4*)(P.h0 + (size_t)((t+1)&1)*BH + b*H + kk*64));
            vmwait();
            float acc[4];
            #pragma unroll
            for (int q = 0; q < 4; ++q) {
                const float4* w = (const float4*)(sC + q*256 + kk*64);
                float a = 0.f;
                #pragma unroll
                for (int i = 0; i < 16; ++i) a += dot4(st[i], w[i]);
                acc[q] = a;
            }
            #pragma unroll
            for (int q = 0; q < 4; ++q) sPart[(kk*4+q)*128 + b] = acc[q];
            __syncthreads();
            if (tid < 128) {
                float g[4];
                #pragma unroll
                for (int q = 0; q < 4; ++q) {
                    float gg = sE[16+q] + gld(P.part1 + ((size_t)(q*256 + blk))*128 + tid);
                    #pragma unroll
                    for (int kx = 0; kx < 4; ++kx) gg += sPart[(kx*4+q)*128 + tid];
                    g[q] = gg;
                }
                cdC = sigm(g[1])*cdC + sigm(g[0])*ftanh(g[2]);
                float hn = sigm(g[3])*ftanh(cdC);
                gst(P.h1 + (size_t)((t+1)&1)*BH + (size_t)tid*256 + blk, hn);
            }
        }
        gbar(P.bar, ++bstep);
    }

    // ---- epilogue: pred[359] ----
    if (blk < 128) {
        if (tid < 256) sD[tid] = gld(P.h1 + 0*BH + (size_t)blk*256 + tid);  // TF even -> buffer 0
        __syncthreads();
        if (tid < 64) {
            int c = tid >> 5, l = tid & 31;
            float a = 0.f;
            for (int k = l; k < 256; k += 32) a += sD[k]*P.o_w[c*256+k];
            #pragma unroll
            for (int mk = 16; mk >= 1; mk >>= 1) a += __shfl_xor(a, mk, 32);
            if (l == 0)
                P.preds[((size_t)blk*TF + TF-1)*2 + c] = gld(P.curr + blk*2 + c) + P.o_b[c] + a;
        }
    }
}

extern "C" void kernel_launch(void* const* d_in, const int* in_sizes, int n_in,
                              void* d_out, int out_size, void* d_ws, size_t ws_size,
                              hipStream_t stream)
{
    const float* hist   = (const float*)d_in[0];
    const float* env    = (const float*)d_in[1];
    const float* e0_Wih = (const float*)d_in[2];
    const float* e0_Whh = (const float*)d_in[3];
    const float* e0_bih = (const float*)d_in[4];
    const float* e0_bhh = (const float*)d_in[5];
    const float* e1_Wih = (const float*)d_in[6];
    const float* e1_Whh = (const float*)d_in[7];
    const float* e1_bih = (const float*)d_in[8];
    const float* e1_bhh = (const float*)d_in[9];
    const float* c1w = (const float*)d_in[10];
    const float* c1b = (const float*)d_in[11];
    const float* c2w = (const float*)d_in[12];
    const float* c2b = (const float*)d_in[13];
    const float* c3w = (const float*)d_in[14];
    const float* c3b = (const float*)d_in[15];
    const float* ef_w = (const float*)d_in[16];
    const float* ef_b = (const float*)d_in[17];
    const float* aW_w = (const float*)d_in[18];
    const float* aW_b = (const float*)d_in[19];
    const float* av_w = (const float*)d_in[20];
    const float* av_b = (const float*)d_in[21];
    const float* d0_Wih = (const float*)d_in[22];
    const float* d0_Whh = (const float*)d_in[23];
    const float* d0_bih = (const float*)d_in[24];
    const float* d0_bhh = (const float*)d_in[25];
    const float* d1_Wih = (const float*)d_in[26];
    const float* d1_Whh = (const float*)d_in[27];
    const float* d1_bih = (const float*)d_in[28];
    const float* d1_bhh = (const float*)d_in[29];
    const float* o_w = (const float*)d_in[30];
    const float* o_b = (const float*)d_in[31];

    float* ws = (float*)d_ws;
    size_t off = 0;
    float* keys = ws;        off += (size_t)B*NK*H;
    float* kp   = ws + off;  off += (size_t)B*NK*H;
    float* convA = kp;                       // conv scratch aliases kp (consumed first)
    float* convB = kp + 4194304;
    float* convC = kp + 6291456;
    float* h0    = ws + off; off += 2*BH;    // doubles as decoder hd1 ping-pong
    float* h1    = ws + off; off += 2*BH;    // doubles as decoder hd2 ping-pong
    float* cfin1 = ws + off; off += BH;
    float* ctx   = ws + off; off += BH;
    float* part0 = ws + off; off += (size_t)4*H*B;
    float* part1 = ws + off; off += (size_t)4*H*B;
    float* curr  = ws + off; off += (size_t)B*2;
    unsigned* bar = (unsigned*)(ws + off);   // 512 uints

    hipMemsetAsync(bar, 0, 512*sizeof(unsigned), stream);

    // ---- CNN branch (one-shot) ----
    conv_relu<18, 32, 64, 32><<<(B*32*32*32)/256, 256, 0, stream>>>(env, c1w, c1b, convA);
    conv_relu<32, 64, 32, 16><<<(B*64*16*16)/256, 256, 0, stream>>>(convA, c2w, c2b, convB);
    conv_relu<64, 128, 16, 8><<<(B*128*8*8)/256, 256, 0, stream>>>(convB, c3w, c3b, convC);
    pool_ef<<<B, 512, 0, stream>>>(convC, ef_w, ef_b, keys);

    KP2 Pk = {
        hist,
        e0_Wih, e0_Whh, e0_bih, e0_bhh,
        e1_Wih, e1_Whh, e1_bih, e1_bhh,
        aW_w, aW_b, av_w, av_b,
        d0_Wih, d0_Whh, d0_bih, d0_bhh,
        d1_Wih, d1_Whh, d1_bih, d1_bhh,
        o_w, o_b,
        keys, kp, h0, h1, cfin1, ctx, part0, part1, curr, (float*)d_out,
        bar
    };
    void* args[] = { &Pk };
    hipLaunchCooperativeKernel((void*)fused2, dim3(256), dim3(512), args, 0, stream);
}